// Round 12
// baseline (388.768 us; speedup 1.0000x reference)
//
#include <hip/hip_runtime.h>
#include <math.h>

#define CDIM 256
#define LSEQ 8192
#define BATCH 8
#define MTOT (BATCH * LSEQ)
#define PADROWS 8208           // 8 + 8192 + 8 per batch
#define PAD0 8

typedef unsigned short ushort_t;
typedef unsigned int uint_t;

typedef __bf16 bf16x8 __attribute__((ext_vector_type(8)));
typedef float f32x4 __attribute__((ext_vector_type(4)));

__device__ __forceinline__ ushort_t f2bf(float f) {
    union { float f; uint_t u; } v; v.f = f;
    uint_t u = v.u;
    return (ushort_t)((u + 0x7FFFu + ((u >> 16) & 1u)) >> 16);  // RNE
}
__device__ __forceinline__ float bf2f(ushort_t h) {
    union { uint_t u; float f; } v; v.u = ((uint_t)h) << 16;
    return v.f;
}
__device__ __forceinline__ float gelu_exact(float x) {
    return 0.5f * x * (1.0f + erff(x * 0.70710678118654752440f));
}

// async global(16B/lane) -> LDS (wave-uniform base + lane*16)
__device__ __forceinline__ void gload16(const ushort_t* g, ushort_t* lds) {
    __builtin_amdgcn_global_load_lds(
        reinterpret_cast<__attribute__((address_space(1))) uint_t*>(
            reinterpret_cast<uintptr_t>(g)),
        reinterpret_cast<__attribute__((address_space(3))) uint_t*>(
            reinterpret_cast<uintptr_t>(lds)),
        16, 0, 0);
}

// ---------------- fused x: bf16 convert + gates sliver ----------------
__global__ __launch_bounds__(256) void cvt_gates(
    const float* __restrict__ x, const float* __restrict__ f_w,
    const float* __restrict__ f_b,
    ushort_t* __restrict__ x_bf, float* __restrict__ gates)
{
    __shared__ float fcol[256][4];
    int tid = threadIdx.x;
    #pragma unroll
    for (int j = 0; j < 4; ++j) fcol[tid][j] = f_w[(size_t)tid * 516 + 512 + j];
    __syncthreads();
    int w = tid >> 6, l = tid & 63;
    size_t t = (size_t)blockIdx.x * 4 + w;
    float4 xv = ((const float4*)(x + t * CDIM))[l];
    ((ushort4*)(x_bf + t * CDIM))[l] =
        make_ushort4(f2bf(xv.x), f2bf(xv.y), f2bf(xv.z), f2bf(xv.w));
    int c = l * 4;
    float a[4];
    #pragma unroll
    for (int j = 0; j < 4; ++j)
        a[j] = xv.x * fcol[c][j] + xv.y * fcol[c + 1][j] + xv.z * fcol[c + 2][j] + xv.w * fcol[c + 3][j];
    #pragma unroll
    for (int off = 32; off >= 1; off >>= 1)
        #pragma unroll
        for (int j = 0; j < 4; ++j) a[j] += __shfl_xor(a[j], off);
    if (l == 0) {
        #pragma unroll
        for (int j = 0; j < 4; ++j) gates[t * 4 + j] = a[j] + f_b[512 + j];
    }
}

// ---------------- single-launch weight prep ----------------
__global__ __launch_bounds__(256) void prep_weights(
    const float* __restrict__ f_w,  const float* __restrict__ c0,
    const float* __restrict__ c1,   const float* __restrict__ c2,
    const float* __restrict__ h_w,  const float* __restrict__ p_w,
    ushort_t* __restrict__ f_wT, ushort_t* __restrict__ c0T,
    ushort_t* __restrict__ c1T,  ushort_t* __restrict__ c2T,
    ushort_t* __restrict__ h_wT, ushort_t* __restrict__ p_wT)
{
    __shared__ float t[32][33];
    int r = blockIdx.x;
    const float* in; ushort_t* out; int Kt, ldin;
    if (r < 128)              { in = f_w; out = f_wT; Kt = 8;  ldin = 516; }
    else if ((r -= 128) < 192){ in = c0;  out = c0T;  Kt = 24; ldin = 256; }
    else if ((r -= 192) < 320){ in = c1;  out = c1T;  Kt = 40; ldin = 256; }
    else if ((r -= 320) < 448){ in = c2;  out = c2T;  Kt = 56; ldin = 256; }
    else if ((r -= 448) < 64) { in = h_w; out = h_wT; Kt = 8;  ldin = 256; }
    else                      { r -= 64; in = p_w; out = p_wT; Kt = 8; ldin = 256; }
    int K = Kt * 32;
    int k0 = (r % Kt) * 32, n0 = (r / Kt) * 32;
    int tx = threadIdx.x & 31, ty = threadIdx.x >> 5;
    #pragma unroll
    for (int i = 0; i < 4; i++) {
        int k = k0 + ty + i * 8;
        t[ty + i * 8][tx] = in[(size_t)k * ldin + n0 + tx];
    }
    __syncthreads();
    #pragma unroll
    for (int i = 0; i < 4; i++) {
        int n = n0 + ty + i * 8;
        out[(size_t)n * K + k0 + tx] = f2bf(t[tx][ty + i * 8]);
    }
}

// ---------------- zero guard bands of 4 contiguous ctx_pad buffers ----------------
__global__ __launch_bounds__(256) void zero_guards_all(ushort_t* __restrict__ ctx_base) {
    int i = blockIdx.x * 256 + threadIdx.x;
    int buf = i >> 15;
    int j = i & 32767;
    int c = j & 255;
    int rr = (j >> 8) & 15;
    int b = j >> 12;
    size_t row = (size_t)b * PADROWS + ((rr < 8) ? rr : (PADROWS - 16 + rr));
    ctx_base[((size_t)buf * BATCH * PADROWS + row) * CDIM + c] = 0;
}

// ---------------- feature GEMM (m97 structure): 128x128 tile ----------------
// col<256 -> q_bf(bf16) ; col>=256 -> ctx_pad (padded rows, bf16)
__global__ __launch_bounds__(256) void fea_gemm(
    const ushort_t* __restrict__ A, const ushort_t* __restrict__ BT,
    const float* __restrict__ bias,
    ushort_t* __restrict__ q_out, ushort_t* __restrict__ ctx_pad)
{
    __shared__ __align__(16) ushort_t As[128 * 32];
    __shared__ __align__(16) ushort_t Bs[128 * 32];
    int tid = threadIdx.x;
    int w = tid >> 6, l = tid & 63;
    int bn = blockIdx.x * 128;
    int by = blockIdx.y;
    long arow0 = (long)by * 128;
    int crow0 = by * 128;

    int wr = w >> 1, wc = w & 1;
    int lr = l & 15, lk = (l >> 4) * 8;
    int sr = l >> 2;
    int sc = (l & 3) * 8;

    f32x4 acc[4][4] = {};

    for (int kt = 0; kt < 8; ++kt) {
        int k0 = kt << 5;
        #pragma unroll
        for (int jj = 0; jj < 2; ++jj) {
            int j = w * 2 + jj;
            int r = j * 16 + sr;
            gload16(A + (arow0 + r) * CDIM + (k0 + sc), &As[j * 512]);
            gload16(BT + (long)(bn + r) * 256 + (k0 + sc), &Bs[j * 512]);
        }
        __syncthreads();
        bf16x8 av[4], bv[4];
        #pragma unroll
        for (int m = 0; m < 4; ++m)
            av[m] = *reinterpret_cast<const bf16x8*>(&As[(wr * 64 + m * 16 + lr) * 32 + lk]);
        #pragma unroll
        for (int n = 0; n < 4; ++n)
            bv[n] = *reinterpret_cast<const bf16x8*>(&Bs[(wc * 64 + n * 16 + lr) * 32 + lk]);
        #pragma unroll
        for (int m = 0; m < 4; ++m)
            #pragma unroll
            for (int n = 0; n < 4; ++n)
                acc[m][n] = __builtin_amdgcn_mfma_f32_16x16x32_bf16(av[m], bv[n], acc[m][n], 0, 0, 0);
        __syncthreads();
    }

    int rbase = (l >> 4) * 4;
    #pragma unroll
    for (int n = 0; n < 4; ++n) {
        int col = bn + wc * 64 + n * 16 + lr;
        float bia = bias[col];
        #pragma unroll
        for (int m = 0; m < 4; ++m) {
            int rowb = crow0 + wr * 64 + m * 16 + rbase;
            #pragma unroll
            for (int r = 0; r < 4; ++r) {
                float v = acc[m][n][r] + bia;
                int row = rowb + r;
                if (col < CDIM) {
                    q_out[(size_t)row * CDIM + col] = f2bf(v);
                } else {
                    int bb = row >> 13, tb = row & (LSEQ - 1);
                    ctx_pad[((size_t)bb * PADROWS + PAD0 + tb) * CDIM + (col - CDIM)] = f2bf(v);
                }
            }
        }
    }
}

// ---- staging helpers for conv_fused (BM=128, 512 thr) ----
__device__ __forceinline__ void stageA128(const ushort_t* Arow0, int cc,
                                          ushort_t* asb, int tid, int w) {
    int row = tid >> 2, cp = tid & 3;
    int cg = cp ^ ((row >> 1) & 3);
    gload16(Arow0 + (size_t)row * CDIM + cc * 32 + cg * 8, asb + (size_t)(w * 64) * 8);
    if (tid < 64) {
        int o2 = 512 + tid;
        int row2 = o2 >> 2, cp2 = o2 & 3;
        int cg2 = cp2 ^ ((row2 >> 1) & 3);
        gload16(Arow0 + (size_t)row2 * CDIM + cc * 32 + cg2 * 8, asb + (size_t)512 * 8);
    }
}
__device__ __forceinline__ void stageB128(const ushort_t* BT, int Ktot, int koffB,
                                          ushort_t* bsb, int tid) {
    #pragma unroll
    for (int i = 0; i < 2; ++i) {
        int o = tid + i * 512;
        int n = o >> 2, cp = o & 3;
        int cg = cp ^ ((n >> 1) & 3);
        gload16(BT + (size_t)n * Ktot + koffB + cg * 8,
                bsb + (size_t)((o >> 6) * 64) * 8);
    }
}

// ---------------- fused conv: BM=128, BN=256, 512 thr, 2 blocks/CU ----------------
__global__ __launch_bounds__(512, 4) void conv_fused(
    const ushort_t* __restrict__ A, const ushort_t* __restrict__ BT,
    const float* __restrict__ bias,
    const float* __restrict__ lng, const float* __restrict__ lnb,
    ushort_t* __restrict__ ctx_out, int KW, int Ktot)
{
    __shared__ __align__(16) ushort_t As2[2][144 * 32];  // 18432 B
    __shared__ __align__(16) ushort_t Bs[2][256 * 32];   // 32768 B

    int tid = threadIdx.x;
    int w = tid >> 6, l = tid & 63;
    int by = blockIdx.x;
    int b = by >> 6;
    int tloc = (by & 63) << 7;
    const ushort_t* Arow0 = A + ((size_t)b * PADROWS + PAD0 + tloc - 8) * CDIM;

    int wr = w >> 2;
    int wc = w & 3;
    int lr = l & 15;
    int quad = l >> 4;

    int P = KW >> 1;
    int hoff = 8 - P;
    f32x4 acc[4][4] = {};

    stageA128(Arow0, 0, As2[0], tid, w);
    stageB128(BT, Ktot, 0, Bs[0], tid);
    __syncthreads();

    int nIt = KW * 8;
    int it = 0;
    for (int c = 0; c < 8; ++c) {
        for (int tap = 0; tap < KW; ++tap, ++it) {
            if (tap == 0 && c < 7)
                stageA128(Arow0, c + 1, As2[(c + 1) & 1], tid, w);
            if (it + 1 < nIt) {
                int tapn = tap + 1, cn = c;
                if (tapn == KW) { tapn = 0; cn = c + 1; }
                stageB128(BT, Ktot, tapn * 256 + cn * 32, Bs[(it + 1) & 1], tid);
            }
            const ushort_t* asb = As2[c & 1];
            const ushort_t* bsb = Bs[it & 1];
            bf16x8 av[4], bv[4];
            #pragma unroll
            for (int m = 0; m < 4; ++m) {
                int row = wr * 64 + m * 16 + lr + tap + hoff;
                int cs = quad ^ ((row >> 1) & 3);
                av[m] = *reinterpret_cast<const bf16x8*>(&asb[row * 32 + cs * 8]);
            }
            #pragma unroll
            for (int n = 0; n < 4; ++n) {
                int nn = wc * 64 + n * 16 + lr;
                int cs = quad ^ ((nn >> 1) & 3);
                bv[n] = *reinterpret_cast<const bf16x8*>(&bsb[nn * 32 + cs * 8]);
            }
            #pragma unroll
            for (int m = 0; m < 4; ++m)
                #pragma unroll
                for (int n = 0; n < 4; ++n)
                    acc[m][n] = __builtin_amdgcn_mfma_f32_16x16x32_bf16(av[m], bv[n], acc[m][n], 0, 0, 0);
            __syncthreads();
        }
    }

    float* rs = (float*)&Bs[0][0];
    float* rq = rs + 512;
    float bias_c[4], lng_c[4], lnb_c[4];
    #pragma unroll
    for (int n = 0; n < 4; ++n) {
        int col = wc * 64 + n * 16 + lr;
        bias_c[n] = bias[col];
        lng_c[n] = lng[col];
        lnb_c[n] = lnb[col];
    }
    #pragma unroll
    for (int m = 0; m < 4; ++m) {
        #pragma unroll
        for (int r = 0; r < 4; ++r) {
            float s = 0.0f, sq = 0.0f;
            #pragma unroll
            for (int n = 0; n < 4; ++n) {
                float v = acc[m][n][r] + bias_c[n];
                v = gelu_exact(v);
                acc[m][n][r] = v;
                s += v; sq += v * v;
            }
            s += __shfl_xor(s, 1);  sq += __shfl_xor(sq, 1);
            s += __shfl_xor(s, 2);  sq += __shfl_xor(sq, 2);
            s += __shfl_xor(s, 4);  sq += __shfl_xor(sq, 4);
            s += __shfl_xor(s, 8);  sq += __shfl_xor(sq, 8);
            if (lr == 0) {
                int rl = wr * 64 + m * 16 + quad * 4 + r;
                rs[rl * 4 + wc] = s;
                rq[rl * 4 + wc] = sq;
            }
        }
    }
    __syncthreads();
    #pragma unroll
    for (int m = 0; m < 4; ++m) {
        #pragma unroll
        for (int r = 0; r < 4; ++r) {
            int rl = wr * 64 + m * 16 + quad * 4 + r;
            float mean = (rs[rl * 4] + rs[rl * 4 + 1] + rs[rl * 4 + 2] + rs[rl * 4 + 3]) * (1.0f / 256.0f);
            float var = (rq[rl * 4] + rq[rl * 4 + 1] + rq[rl * 4 + 2] + rq[rl * 4 + 3]) * (1.0f / 256.0f) - mean * mean;
            float inv = rsqrtf(var + 1e-3f);
            int trow = tloc + rl;
            ushort_t* cp = ctx_out + ((size_t)b * PADROWS + PAD0 + trow) * CDIM;
            #pragma unroll
            for (int n = 0; n < 4; ++n) {
                int col = wc * 64 + n * 16 + lr;
                float y = (acc[m][n][r] - mean) * inv * lng_c[n] + lnb_c[n];
                cp[col] = f2bf(y);
            }
        }
    }
}

// ---------------- column mean over L (two stage) ----------------
__global__ __launch_bounds__(256) void col_mean_partial(const ushort_t* __restrict__ ctx_pad,
                                                        float* __restrict__ partial) {
    int b = blockIdx.x, chunk = blockIdx.y, c = threadIdx.x;
    const ushort_t* base = ctx_pad + ((size_t)b * PADROWS + PAD0 + chunk * 256) * CDIM + c;
    float s = 0.0f;
    for (int r = 0; r < 256; ++r) s += bf2f(base[(size_t)r * CDIM]);
    partial[((size_t)b * 32 + chunk) * CDIM + c] = s;
}

__global__ __launch_bounds__(256) void col_mean_final(const float* __restrict__ partial,
                                                      float* __restrict__ meanv) {
    int b = blockIdx.x, c = threadIdx.x;
    float s = 0.0f;
    for (int i = 0; i < 32; ++i) s += partial[((size_t)b * 32 + i) * CDIM + c];
    meanv[b * CDIM + c] = s * (1.0f / (float)LSEQ);
}

// ---------------- tail_fused: (sum gate*ctx + mean*g3) @ h_w ; *q ; @ proj_w ----------------
// 512 thr, tile 128x256, 80KB aliased LDS -> 2 blocks/CU. Phase 1: h-GEMM with
// A computed in-register from ctx0/1/2+gates+meanv (reg-stage -> ds_write).
// Epilogue1: +h_b, *q -> bf16 qc into swizzled LDS (c16 ^= row&7). Phase 2:
// proj-GEMM reading qc from LDS (no A staging), +proj_b -> fp32 out.
__global__ __launch_bounds__(512) void tail_fused(
    const ushort_t* __restrict__ ctx0, const ushort_t* __restrict__ ctx1,
    const ushort_t* __restrict__ ctx2,
    const float* __restrict__ gates, const float* __restrict__ meanv,
    const ushort_t* __restrict__ q_bf,
    const ushort_t* __restrict__ h_wT, const float* __restrict__ h_b,
    const ushort_t* __restrict__ proj_wT, const float* __restrict__ proj_b,
    float* __restrict__ out)
{
    __shared__ __align__(16) char pool[81920];
    ushort_t* As1 = (ushort_t*)pool;             // [128*32] = 8KB   (phase 1)
    ushort_t* Bs1 = (ushort_t*)(pool + 8192);    // [256*32] = 16KB  (phase 1)
    ushort_t* QC  = (ushort_t*)pool;             // [128*256] = 64KB (overlays phase-1 bufs)
    ushort_t* Bs2 = (ushort_t*)(pool + 65536);   // [256*32] = 16KB  (phase 2)

    int tid = threadIdx.x;
    int w = tid >> 6, l = tid & 63;
    long grow0 = (long)blockIdx.x * 128;

    int wr = w >> 2;                  // 0..1 : rows wr*64..+63
    int wc = w & 3;                   // 0..3 : cols wc*64..+63
    int lr = l & 15;
    int quad = l >> 4;
    int lk = quad * 8;

    // per-thread A-staging coords (fixed across k-steps)
    int arow = tid >> 2;              // 0..127
    int seg = tid & 3;                // 16B segment within 32-ch chunk
    long grow_st = grow0 + arow;
    int b_st = (int)(grow_st >> 13), tb_st = (int)(grow_st & (LSEQ - 1));
    size_t prow = ((size_t)b_st * PADROWS + PAD0 + tb_st) * CDIM;
    float4 gv = *(const float4*)(gates + grow_st * 4);

    f32x4 acc[4][4] = {};

    // ---- phase 1: h-GEMM over K=256 (8 steps), A combined in-register ----
    for (int kt = 0; kt < 8; ++kt) {
        int col = kt * 32 + seg * 8;
        // combine A = g0*c0 + g1*c1 + g2*c2 + mean*g3 -> bf16x8 -> LDS
        ushort4 a0 = *(const ushort4*)(ctx0 + prow + col);
        ushort4 a1 = *(const ushort4*)(ctx0 + prow + col + 4);
        ushort4 b0 = *(const ushort4*)(ctx1 + prow + col);
        ushort4 b1 = *(const ushort4*)(ctx1 + prow + col + 4);
        ushort4 d0 = *(const ushort4*)(ctx2 + prow + col);
        ushort4 d1 = *(const ushort4*)(ctx2 + prow + col + 4);
        float4 m0 = *(const float4*)(meanv + b_st * CDIM + col);
        float4 m1 = *(const float4*)(meanv + b_st * CDIM + col + 4);
        ushort_t va[8] = { a0.x, a0.y, a0.z, a0.w, a1.x, a1.y, a1.z, a1.w };
        ushort_t vb[8] = { b0.x, b0.y, b0.z, b0.w, b1.x, b1.y, b1.z, b1.w };
        ushort_t vd[8] = { d0.x, d0.y, d0.z, d0.w, d1.x, d1.y, d1.z, d1.w };
        float mv[8] = { m0.x, m0.y, m0.z, m0.w, m1.x, m1.y, m1.z, m1.w };
        ushort_t ov[8];
        #pragma unroll
        for (int j = 0; j < 8; ++j)
            ov[j] = f2bf(bf2f(va[j]) * gv.x + bf2f(vb[j]) * gv.y +
                         bf2f(vd[j]) * gv.z + mv[j] * gv.w);
        *(ushort4*)(As1 + arow * 32 + seg * 8)     = make_ushort4(ov[0], ov[1], ov[2], ov[3]);
        *(ushort4*)(As1 + arow * 32 + seg * 8 + 4) = make_ushort4(ov[4], ov[5], ov[6], ov[7]);
        // stage B (h_wT chunk [256 n][32 k]) linear
        #pragma unroll
        for (int i = 0; i < 2; ++i) {
            int o = tid + i * 512;
            int n = o >> 2, cp = o & 3;
            gload16(h_wT + (size_t)n * 256 + kt * 32 + cp * 8,
                    Bs1 + (size_t)((o >> 6) * 64) * 8);
        }
        __syncthreads();
        bf16x8 av[4], bv[4];
        #pragma unroll
        for (int m = 0; m < 4; ++m)
            av[m] = *reinterpret_cast<const bf16x8*>(&As1[(wr * 64 + m * 16 + lr) * 32 + lk]);
        #pragma unroll
        for (int n = 0; n < 4; ++n)
            bv[n] = *reinterpret_cast<const bf16x8*>(&Bs1[(wc * 64 + n * 16 + lr) * 32 + lk]);
        #pragma unroll
        for (int m = 0; m < 4; ++m)
            #pragma unroll
            for (int n = 0; n < 4; ++n)
                acc[m][n] = __builtin_amdgcn_mfma_f32_16x16x32_bf16(av[m], bv[n], acc[m][n], 0, 0, 0);
        __syncthreads();
    }

    // ---- epilogue 1: +h_b, *q, bf16 -> QC (swizzled) ----
    {
        float hb_c[4];
        #pragma unroll
        for (int n = 0; n < 4; ++n) hb_c[n] = h_b[wc * 64 + n * 16 + lr];
        #pragma unroll
        for (int m = 0; m < 4; ++m) {
            #pragma unroll
            for (int r = 0; r < 4; ++r) {
                int row = wr * 64 + m * 16 + quad * 4 + r;
                long grow = grow0 + row;
                #pragma unroll
                for (int n = 0; n < 4; ++n) {
                    int col = wc * 64 + n * 16 + lr;
                    float v = acc[m][n][r] + hb_c[n];
                    float qv = bf2f(q_bf[(size_t)grow * CDIM + col]);
                    int c16 = (col >> 3) ^ (row & 7);
                    QC[row * 256 + c16 * 8 + (col & 7)] = f2bf(qv * v);
                }
            }
        }
    }
    __syncthreads();

    // ---- phase 2: proj-GEMM, A from QC (LDS), B staged single-buffer ----
    f32x4 acc2[4][4] = {};
    for (int kt = 0; kt < 8; ++kt) {
        #pragma unroll
        for (int i = 0; i < 2; ++i) {
            int o = tid + i * 512;
            int n = o >> 2, cp = o & 3;
            gload16(proj_wT + (size_t)n * 256 + kt * 32 + cp * 8,
                    Bs2 + (size_t)((o >> 6) * 64) * 8);
        }
        __syncthreads();
        bf16x8 av[4], bv[4];
        #pragma unroll
        for (int m = 0; m < 4; ++m) {
            int row = wr * 64 + m * 16 + lr;
            int c16 = (kt * 4 + quad) ^ (row & 7);
            av[m] = *reinterpret_cast<const bf16x8*>(&QC[row * 256 + c16 * 8]);
        }
        #pragma unroll
        for (int n = 0; n < 4; ++n)
            bv[n] = *reinterpret_cast<const bf16x8*>(&Bs2[(wc * 64 + n * 16 + lr) * 32 + lk]);
        #pragma unroll
        for (int m = 0; m < 4; ++m)
            #pragma unroll
            for (int n = 0; n < 4; ++n)
                acc2[m][n] = __builtin_amdgcn_mfma_f32_16x16x32_bf16(av[m], bv[n], acc2[m][n], 0, 0, 0);
        __syncthreads();
    }

    // ---- epilogue 2: +proj_b -> fp32 out ----
    int rbase = quad * 4;
    #pragma unroll
    for (int n = 0; n < 4; ++n) {
        int col = wc * 64 + n * 16 + lr;
        float pb = proj_b[col];
        #pragma unroll
        for (int m = 0; m < 4; ++m) {
            #pragma unroll
            for (int r = 0; r < 4; ++r) {
                long grow = grow0 + wr * 64 + m * 16 + rbase + r;
                out[(size_t)grow * CDIM + col] = acc2[m][n][r] + pb;
            }
        }
    }
}

extern "C" void kernel_launch(void* const* d_in, const int* in_sizes, int n_in,
                              void* d_out, int out_size, void* d_ws, size_t ws_size,
                              hipStream_t stream) {
    const float* x      = (const float*)d_in[0];
    const float* f_w    = (const float*)d_in[1];
    const float* f_b    = (const float*)d_in[2];
    const float* h_w    = (const float*)d_in[3];
    const float* h_b    = (const float*)d_in[4];
    const float* proj_w = (const float*)d_in[5];
    const float* proj_b = (const float*)d_in[6];
    const float* conv_w[3] = { (const float*)d_in[7],  (const float*)d_in[11], (const float*)d_in[15] };
    const float* conv_b[3] = { (const float*)d_in[8],  (const float*)d_in[12], (const float*)d_in[16] };
    const float* ln_g[3]   = { (const float*)d_in[9],  (const float*)d_in[13], (const float*)d_in[17] };
    const float* ln_b[3]   = { (const float*)d_in[10], (const float*)d_in[14], (const float*)d_in[18] };

    const size_t MC = (size_t)MTOT * CDIM;
    const size_t PADC = (size_t)BATCH * PADROWS * CDIM;
    char* w = (char*)d_ws;
    ushort_t* x_bf  = (ushort_t*)w;  w += MC * 2;
    ushort_t* q_bf  = (ushort_t*)w;  w += MC * 2;
    ushort_t* ctxF  = (ushort_t*)w;  w += PADC * 2;   // ctxF..ctx2 contiguous
    ushort_t* ctx0  = (ushort_t*)w;  w += PADC * 2;
    ushort_t* ctx1  = (ushort_t*)w;  w += PADC * 2;
    ushort_t* ctx2  = (ushort_t*)w;  w += PADC * 2;
    float* gates    = (float*)w;     w += (size_t)MTOT * 4 * 4;
    float* partial  = (float*)w;     w += (size_t)8 * 32 * CDIM * 4;
    float* meanv    = (float*)w;     w += (size_t)8 * CDIM * 4;
    ushort_t* f_wT  = (ushort_t*)w;  w += (size_t)512 * 256 * 2;
    ushort_t* convT0 = (ushort_t*)w; w += (size_t)768 * 256 * 2;
    ushort_t* convT1 = (ushort_t*)w; w += (size_t)1280 * 256 * 2;
    ushort_t* convT2 = (ushort_t*)w; w += (size_t)1792 * 256 * 2;
    ushort_t* h_wT   = (ushort_t*)w; w += (size_t)256 * 256 * 2;
    ushort_t* proj_wT = (ushort_t*)w; w += (size_t)256 * 256 * 2;

    dim3 blk(256);

    cvt_gates<<<dim3(MTOT / 4), blk, 0, stream>>>(x, f_w, f_b, x_bf, gates);
    prep_weights<<<dim3(1216), blk, 0, stream>>>(f_w, conv_w[0], conv_w[1], conv_w[2],
        h_w, proj_w, f_wT, convT0, convT1, convT2, h_wT, proj_wT);
    zero_guards_all<<<dim3(512), blk, 0, stream>>>(ctxF);

    // feature GEMM (q + ctx)
    fea_gemm<<<dim3(4, 512), blk, 0, stream>>>(x_bf, f_wT, f_b, q_bf, ctxF);

    // three fused conv+GELU+LN levels (best verified structure)
    conv_fused<<<dim3(512), dim3(512), 0, stream>>>(ctxF, convT0, conv_b[0],
        ln_g[0], ln_b[0], ctx0, 3, 768);
    conv_fused<<<dim3(512), dim3(512), 0, stream>>>(ctx0, convT1, conv_b[1],
        ln_g[1], ln_b[1], ctx1, 5, 1280);
    conv_fused<<<dim3(512), dim3(512), 0, stream>>>(ctx1, convT2, conv_b[2],
        ln_g[2], ln_b[2], ctx2, 7, 1792);

    // global context mean (final ctx is ctx2)
    col_mean_partial<<<dim3(BATCH, 32), blk, 0, stream>>>(ctx2, partial);
    col_mean_final<<<dim3(BATCH), blk, 0, stream>>>(partial, meanv);

    // fused tail: combine + h-GEMM + q-mul + proj-GEMM -> d_out
    tail_fused<<<dim3(512), dim3(512), 0, stream>>>(ctx0, ctx1, ctx2,
        gates, meanv, q_bf, h_wT, h_b, proj_wT, proj_b, (float*)d_out);
}

// Round 13
// 380.360 us; speedup vs baseline: 1.0221x; 1.0221x over previous
//
#include <hip/hip_runtime.h>
#include <math.h>

#define CDIM 256
#define LSEQ 8192
#define BATCH 8
#define MTOT (BATCH * LSEQ)
#define PADROWS 8208           // 8 + 8192 + 8 per batch
#define PAD0 8

typedef unsigned short ushort_t;
typedef unsigned int uint_t;

typedef __bf16 bf16x8 __attribute__((ext_vector_type(8)));
typedef float f32x4 __attribute__((ext_vector_type(4)));

__device__ __forceinline__ ushort_t f2bf(float f) {
    union { float f; uint_t u; } v; v.f = f;
    uint_t u = v.u;
    return (ushort_t)((u + 0x7FFFu + ((u >> 16) & 1u)) >> 16);  // RNE
}
__device__ __forceinline__ float bf2f(ushort_t h) {
    union { uint_t u; float f; } v; v.u = ((uint_t)h) << 16;
    return v.f;
}
__device__ __forceinline__ float gelu_exact(float x) {
    return 0.5f * x * (1.0f + erff(x * 0.70710678118654752440f));
}

// async global(16B/lane) -> LDS (wave-uniform base + lane*16)
__device__ __forceinline__ void gload16(const ushort_t* g, ushort_t* lds) {
    __builtin_amdgcn_global_load_lds(
        reinterpret_cast<__attribute__((address_space(1))) uint_t*>(
            reinterpret_cast<uintptr_t>(g)),
        reinterpret_cast<__attribute__((address_space(3))) uint_t*>(
            reinterpret_cast<uintptr_t>(lds)),
        16, 0, 0);
}

// ---------------- fused x: bf16 convert + gates sliver ----------------
__global__ __launch_bounds__(256) void cvt_gates(
    const float* __restrict__ x, const float* __restrict__ f_w,
    const float* __restrict__ f_b,
    ushort_t* __restrict__ x_bf, float* __restrict__ gates)
{
    __shared__ float fcol[256][4];
    int tid = threadIdx.x;
    #pragma unroll
    for (int j = 0; j < 4; ++j) fcol[tid][j] = f_w[(size_t)tid * 516 + 512 + j];
    __syncthreads();
    int w = tid >> 6, l = tid & 63;
    size_t t = (size_t)blockIdx.x * 4 + w;
    float4 xv = ((const float4*)(x + t * CDIM))[l];
    ((ushort4*)(x_bf + t * CDIM))[l] =
        make_ushort4(f2bf(xv.x), f2bf(xv.y), f2bf(xv.z), f2bf(xv.w));
    int c = l * 4;
    float a[4];
    #pragma unroll
    for (int j = 0; j < 4; ++j)
        a[j] = xv.x * fcol[c][j] + xv.y * fcol[c + 1][j] + xv.z * fcol[c + 2][j] + xv.w * fcol[c + 3][j];
    #pragma unroll
    for (int off = 32; off >= 1; off >>= 1)
        #pragma unroll
        for (int j = 0; j < 4; ++j) a[j] += __shfl_xor(a[j], off);
    if (l == 0) {
        #pragma unroll
        for (int j = 0; j < 4; ++j) gates[t * 4 + j] = a[j] + f_b[512 + j];
    }
}

// ---------------- single-launch weight prep ----------------
__global__ __launch_bounds__(256) void prep_weights(
    const float* __restrict__ f_w,  const float* __restrict__ c0,
    const float* __restrict__ c1,   const float* __restrict__ c2,
    const float* __restrict__ h_w,  const float* __restrict__ p_w,
    ushort_t* __restrict__ f_wT, ushort_t* __restrict__ c0T,
    ushort_t* __restrict__ c1T,  ushort_t* __restrict__ c2T,
    ushort_t* __restrict__ h_wT, ushort_t* __restrict__ p_wT)
{
    __shared__ float t[32][33];
    int r = blockIdx.x;
    const float* in; ushort_t* out; int Kt, ldin;
    if (r < 128)              { in = f_w; out = f_wT; Kt = 8;  ldin = 516; }
    else if ((r -= 128) < 192){ in = c0;  out = c0T;  Kt = 24; ldin = 256; }
    else if ((r -= 192) < 320){ in = c1;  out = c1T;  Kt = 40; ldin = 256; }
    else if ((r -= 320) < 448){ in = c2;  out = c2T;  Kt = 56; ldin = 256; }
    else if ((r -= 448) < 64) { in = h_w; out = h_wT; Kt = 8;  ldin = 256; }
    else                      { r -= 64; in = p_w; out = p_wT; Kt = 8; ldin = 256; }
    int K = Kt * 32;
    int k0 = (r % Kt) * 32, n0 = (r / Kt) * 32;
    int tx = threadIdx.x & 31, ty = threadIdx.x >> 5;
    #pragma unroll
    for (int i = 0; i < 4; i++) {
        int k = k0 + ty + i * 8;
        t[ty + i * 8][tx] = in[(size_t)k * ldin + n0 + tx];
    }
    __syncthreads();
    #pragma unroll
    for (int i = 0; i < 4; i++) {
        int n = n0 + ty + i * 8;
        out[(size_t)n * K + k0 + tx] = f2bf(t[tx][ty + i * 8]);
    }
}

// ---------------- zero guard bands of 4 contiguous ctx_pad buffers ----------------
__global__ __launch_bounds__(256) void zero_guards_all(ushort_t* __restrict__ ctx_base) {
    int i = blockIdx.x * 256 + threadIdx.x;
    int buf = i >> 15;
    int j = i & 32767;
    int c = j & 255;
    int rr = (j >> 8) & 15;
    int b = j >> 12;
    size_t row = (size_t)b * PADROWS + ((rr < 8) ? rr : (PADROWS - 16 + rr));
    ctx_base[((size_t)buf * BATCH * PADROWS + row) * CDIM + c] = 0;
}

// ---------------- feature GEMM (m97 structure): 128x128 tile ----------------
__global__ __launch_bounds__(256) void fea_gemm(
    const ushort_t* __restrict__ A, const ushort_t* __restrict__ BT,
    const float* __restrict__ bias,
    ushort_t* __restrict__ q_out, ushort_t* __restrict__ ctx_pad)
{
    __shared__ __align__(16) ushort_t As[128 * 32];
    __shared__ __align__(16) ushort_t Bs[128 * 32];
    int tid = threadIdx.x;
    int w = tid >> 6, l = tid & 63;
    int bn = blockIdx.x * 128;
    int by = blockIdx.y;
    long arow0 = (long)by * 128;
    int crow0 = by * 128;

    int wr = w >> 1, wc = w & 1;
    int lr = l & 15, lk = (l >> 4) * 8;
    int sr = l >> 2;
    int sc = (l & 3) * 8;

    f32x4 acc[4][4] = {};

    for (int kt = 0; kt < 8; ++kt) {
        int k0 = kt << 5;
        #pragma unroll
        for (int jj = 0; jj < 2; ++jj) {
            int j = w * 2 + jj;
            int r = j * 16 + sr;
            gload16(A + (arow0 + r) * CDIM + (k0 + sc), &As[j * 512]);
            gload16(BT + (long)(bn + r) * 256 + (k0 + sc), &Bs[j * 512]);
        }
        __syncthreads();
        bf16x8 av[4], bv[4];
        #pragma unroll
        for (int m = 0; m < 4; ++m)
            av[m] = *reinterpret_cast<const bf16x8*>(&As[(wr * 64 + m * 16 + lr) * 32 + lk]);
        #pragma unroll
        for (int n = 0; n < 4; ++n)
            bv[n] = *reinterpret_cast<const bf16x8*>(&Bs[(wc * 64 + n * 16 + lr) * 32 + lk]);
        #pragma unroll
        for (int m = 0; m < 4; ++m)
            #pragma unroll
            for (int n = 0; n < 4; ++n)
                acc[m][n] = __builtin_amdgcn_mfma_f32_16x16x32_bf16(av[m], bv[n], acc[m][n], 0, 0, 0);
        __syncthreads();
    }

    int rbase = (l >> 4) * 4;
    #pragma unroll
    for (int n = 0; n < 4; ++n) {
        int col = bn + wc * 64 + n * 16 + lr;
        float bia = bias[col];
        #pragma unroll
        for (int m = 0; m < 4; ++m) {
            int rowb = crow0 + wr * 64 + m * 16 + rbase;
            #pragma unroll
            for (int r = 0; r < 4; ++r) {
                float v = acc[m][n][r] + bia;
                int row = rowb + r;
                if (col < CDIM) {
                    q_out[(size_t)row * CDIM + col] = f2bf(v);
                } else {
                    int bb = row >> 13, tb = row & (LSEQ - 1);
                    ctx_pad[((size_t)bb * PADROWS + PAD0 + tb) * CDIM + (col - CDIM)] = f2bf(v);
                }
            }
        }
    }
}

// ---- staging helpers for conv_fused (BM=128, 512 thr) ----
__device__ __forceinline__ void stageA128(const ushort_t* Arow0, int cc,
                                          ushort_t* asb, int tid, int w) {
    int row = tid >> 2, cp = tid & 3;
    int cg = cp ^ ((row >> 1) & 3);
    gload16(Arow0 + (size_t)row * CDIM + cc * 32 + cg * 8, asb + (size_t)(w * 64) * 8);
    if (tid < 64) {
        int o2 = 512 + tid;
        int row2 = o2 >> 2, cp2 = o2 & 3;
        int cg2 = cp2 ^ ((row2 >> 1) & 3);
        gload16(Arow0 + (size_t)row2 * CDIM + cc * 32 + cg2 * 8, asb + (size_t)512 * 8);
    }
}
__device__ __forceinline__ void stageB128(const ushort_t* BT, int Ktot, int koffB,
                                          ushort_t* bsb, int tid) {
    #pragma unroll
    for (int i = 0; i < 2; ++i) {
        int o = tid + i * 512;
        int n = o >> 2, cp = o & 3;
        int cg = cp ^ ((n >> 1) & 3);
        gload16(BT + (size_t)n * Ktot + koffB + cg * 8,
                bsb + (size_t)((o >> 6) * 64) * 8);
    }
}

// ---------------- fused conv: BM=128, BN=256, 512 thr, 2 blocks/CU ----------------
__global__ __launch_bounds__(512, 4) void conv_fused(
    const ushort_t* __restrict__ A, const ushort_t* __restrict__ BT,
    const float* __restrict__ bias,
    const float* __restrict__ lng, const float* __restrict__ lnb,
    ushort_t* __restrict__ ctx_out, int KW, int Ktot)
{
    __shared__ __align__(16) ushort_t As2[2][144 * 32];  // 18432 B
    __shared__ __align__(16) ushort_t Bs[2][256 * 32];   // 32768 B

    int tid = threadIdx.x;
    int w = tid >> 6, l = tid & 63;
    int by = blockIdx.x;
    int b = by >> 6;
    int tloc = (by & 63) << 7;
    const ushort_t* Arow0 = A + ((size_t)b * PADROWS + PAD0 + tloc - 8) * CDIM;

    int wr = w >> 2;
    int wc = w & 3;
    int lr = l & 15;
    int quad = l >> 4;

    int P = KW >> 1;
    int hoff = 8 - P;
    f32x4 acc[4][4] = {};

    stageA128(Arow0, 0, As2[0], tid, w);
    stageB128(BT, Ktot, 0, Bs[0], tid);
    __syncthreads();

    int nIt = KW * 8;
    int it = 0;
    for (int c = 0; c < 8; ++c) {
        for (int tap = 0; tap < KW; ++tap, ++it) {
            if (tap == 0 && c < 7)
                stageA128(Arow0, c + 1, As2[(c + 1) & 1], tid, w);
            if (it + 1 < nIt) {
                int tapn = tap + 1, cn = c;
                if (tapn == KW) { tapn = 0; cn = c + 1; }
                stageB128(BT, Ktot, tapn * 256 + cn * 32, Bs[(it + 1) & 1], tid);
            }
            const ushort_t* asb = As2[c & 1];
            const ushort_t* bsb = Bs[it & 1];
            bf16x8 av[4], bv[4];
            #pragma unroll
            for (int m = 0; m < 4; ++m) {
                int row = wr * 64 + m * 16 + lr + tap + hoff;
                int cs = quad ^ ((row >> 1) & 3);
                av[m] = *reinterpret_cast<const bf16x8*>(&asb[row * 32 + cs * 8]);
            }
            #pragma unroll
            for (int n = 0; n < 4; ++n) {
                int nn = wc * 64 + n * 16 + lr;
                int cs = quad ^ ((nn >> 1) & 3);
                bv[n] = *reinterpret_cast<const bf16x8*>(&bsb[nn * 32 + cs * 8]);
            }
            #pragma unroll
            for (int m = 0; m < 4; ++m)
                #pragma unroll
                for (int n = 0; n < 4; ++n)
                    acc[m][n] = __builtin_amdgcn_mfma_f32_16x16x32_bf16(av[m], bv[n], acc[m][n], 0, 0, 0);
            __syncthreads();
        }
    }

    float* rs = (float*)&Bs[0][0];
    float* rq = rs + 512;
    float bias_c[4], lng_c[4], lnb_c[4];
    #pragma unroll
    for (int n = 0; n < 4; ++n) {
        int col = wc * 64 + n * 16 + lr;
        bias_c[n] = bias[col];
        lng_c[n] = lng[col];
        lnb_c[n] = lnb[col];
    }
    #pragma unroll
    for (int m = 0; m < 4; ++m) {
        #pragma unroll
        for (int r = 0; r < 4; ++r) {
            float s = 0.0f, sq = 0.0f;
            #pragma unroll
            for (int n = 0; n < 4; ++n) {
                float v = acc[m][n][r] + bias_c[n];
                v = gelu_exact(v);
                acc[m][n][r] = v;
                s += v; sq += v * v;
            }
            s += __shfl_xor(s, 1);  sq += __shfl_xor(sq, 1);
            s += __shfl_xor(s, 2);  sq += __shfl_xor(sq, 2);
            s += __shfl_xor(s, 4);  sq += __shfl_xor(sq, 4);
            s += __shfl_xor(s, 8);  sq += __shfl_xor(sq, 8);
            if (lr == 0) {
                int rl = wr * 64 + m * 16 + quad * 4 + r;
                rs[rl * 4 + wc] = s;
                rq[rl * 4 + wc] = sq;
            }
        }
    }
    __syncthreads();
    #pragma unroll
    for (int m = 0; m < 4; ++m) {
        #pragma unroll
        for (int r = 0; r < 4; ++r) {
            int rl = wr * 64 + m * 16 + quad * 4 + r;
            float mean = (rs[rl * 4] + rs[rl * 4 + 1] + rs[rl * 4 + 2] + rs[rl * 4 + 3]) * (1.0f / 256.0f);
            float var = (rq[rl * 4] + rq[rl * 4 + 1] + rq[rl * 4 + 2] + rq[rl * 4 + 3]) * (1.0f / 256.0f) - mean * mean;
            float inv = rsqrtf(var + 1e-3f);
            int trow = tloc + rl;
            ushort_t* cp = ctx_out + ((size_t)b * PADROWS + PAD0 + trow) * CDIM;
            #pragma unroll
            for (int n = 0; n < 4; ++n) {
                int col = wc * 64 + n * 16 + lr;
                float y = (acc[m][n][r] - mean) * inv * lng_c[n] + lnb_c[n];
                cp[col] = f2bf(y);
            }
        }
    }
}

// ---------------- column mean over L (two stage) ----------------
__global__ __launch_bounds__(256) void col_mean_partial(const ushort_t* __restrict__ ctx_pad,
                                                        float* __restrict__ partial) {
    int b = blockIdx.x, chunk = blockIdx.y, c = threadIdx.x;
    const ushort_t* base = ctx_pad + ((size_t)b * PADROWS + PAD0 + chunk * 256) * CDIM + c;
    float s = 0.0f;
    for (int r = 0; r < 256; ++r) s += bf2f(base[(size_t)r * CDIM]);
    partial[((size_t)b * 32 + chunk) * CDIM + c] = s;
}

__global__ __launch_bounds__(256) void col_mean_final(const float* __restrict__ partial,
                                                      float* __restrict__ meanv) {
    int b = blockIdx.x, c = threadIdx.x;
    float s = 0.0f;
    for (int i = 0; i < 32; ++i) s += partial[((size_t)b * 32 + i) * CDIM + c];
    meanv[b * CDIM + c] = s * (1.0f / (float)LSEQ);
}

// ---------------- combine + h GEMM + q-mul: 128x128 tile, 256 thr ----------------
// A computed in-register per K-step: A = g0*ctx0 + g1*ctx1 + g2*ctx2 + mean*g3
// (fp32 combine -> bf16 -> ds_write, same rounding as finalize_A). B = h_wT via
// global_load_lds. Epilogue: v = acc + h_b[col]; qc = bf16(q * v) -> qc_out.
__global__ __launch_bounds__(256) void combine_h_gemm(
    const ushort_t* __restrict__ ctx0, const ushort_t* __restrict__ ctx1,
    const ushort_t* __restrict__ ctx2,
    const float* __restrict__ gates, const float* __restrict__ meanv,
    const ushort_t* __restrict__ q_bf,
    const ushort_t* __restrict__ h_wT, const float* __restrict__ h_b,
    ushort_t* __restrict__ qc_out)
{
    __shared__ __align__(16) ushort_t As[128 * 32];
    __shared__ __align__(16) ushort_t Bs[128 * 32];
    int tid = threadIdx.x;
    int w = tid >> 6, l = tid & 63;
    int bn = blockIdx.x * 128;
    long arow0 = (long)blockIdx.y * 128;

    int wr = w >> 1, wc = w & 1;
    int lr = l & 15, lk = (l >> 4) * 8;

    // A-combine coords: each thread owns 16 channels of one row per K-step
    int arow = tid >> 1;              // 0..127
    int seg = tid & 1;                // 0 / 1 (16-ch halves of the 32-ch chunk)
    long grow_st = arow0 + arow;
    int b_st = (int)(grow_st >> 13), tb_st = (int)(grow_st & (LSEQ - 1));
    size_t prow = ((size_t)b_st * PADROWS + PAD0 + tb_st) * CDIM;
    float4 gv = *(const float4*)(gates + grow_st * 4);

    f32x4 acc[4][4] = {};

    for (int kt = 0; kt < 8; ++kt) {
        int col = kt * 32 + seg * 16;
        // load 16 bf16 from each ctx level + 16 fp32 mean; combine; write LDS
        ushort4 c0a = *(const ushort4*)(ctx0 + prow + col);
        ushort4 c0b = *(const ushort4*)(ctx0 + prow + col + 4);
        ushort4 c0c = *(const ushort4*)(ctx0 + prow + col + 8);
        ushort4 c0d = *(const ushort4*)(ctx0 + prow + col + 12);
        ushort4 c1a = *(const ushort4*)(ctx1 + prow + col);
        ushort4 c1b = *(const ushort4*)(ctx1 + prow + col + 4);
        ushort4 c1c = *(const ushort4*)(ctx1 + prow + col + 8);
        ushort4 c1d = *(const ushort4*)(ctx1 + prow + col + 12);
        ushort4 c2a = *(const ushort4*)(ctx2 + prow + col);
        ushort4 c2b = *(const ushort4*)(ctx2 + prow + col + 4);
        ushort4 c2c = *(const ushort4*)(ctx2 + prow + col + 8);
        ushort4 c2d = *(const ushort4*)(ctx2 + prow + col + 12);
        const float* mv = meanv + b_st * CDIM + col;
        ushort_t v0[16] = { c0a.x,c0a.y,c0a.z,c0a.w, c0b.x,c0b.y,c0b.z,c0b.w,
                            c0c.x,c0c.y,c0c.z,c0c.w, c0d.x,c0d.y,c0d.z,c0d.w };
        ushort_t v1[16] = { c1a.x,c1a.y,c1a.z,c1a.w, c1b.x,c1b.y,c1b.z,c1b.w,
                            c1c.x,c1c.y,c1c.z,c1c.w, c1d.x,c1d.y,c1d.z,c1d.w };
        ushort_t v2[16] = { c2a.x,c2a.y,c2a.z,c2a.w, c2b.x,c2b.y,c2b.z,c2b.w,
                            c2c.x,c2c.y,c2c.z,c2c.w, c2d.x,c2d.y,c2d.z,c2d.w };
        ushort_t ov[16];
        #pragma unroll
        for (int j = 0; j < 16; ++j)
            ov[j] = f2bf(bf2f(v0[j]) * gv.x + bf2f(v1[j]) * gv.y +
                         bf2f(v2[j]) * gv.z + mv[j] * gv.w);
        #pragma unroll
        for (int j = 0; j < 4; ++j)
            *(ushort4*)(&As[arow * 32 + seg * 16 + j * 4]) =
                make_ushort4(ov[j*4], ov[j*4+1], ov[j*4+2], ov[j*4+3]);
        // stage B (h_wT rows bn..bn+127, k-chunk kt*32) via global_load_lds
        #pragma unroll
        for (int i = 0; i < 2; ++i) {
            int o = tid + i * 256;
            int n = o >> 2, cp = o & 3;
            gload16(h_wT + (size_t)(bn + n) * 256 + kt * 32 + cp * 8,
                    &Bs[(size_t)(o & ~63) * 8]);
        }
        __syncthreads();
        bf16x8 av[4], bv[4];
        #pragma unroll
        for (int m = 0; m < 4; ++m)
            av[m] = *reinterpret_cast<const bf16x8*>(&As[(wr * 64 + m * 16 + lr) * 32 + lk]);
        #pragma unroll
        for (int n = 0; n < 4; ++n)
            bv[n] = *reinterpret_cast<const bf16x8*>(&Bs[(wc * 64 + n * 16 + lr) * 32 + lk]);
        #pragma unroll
        for (int m = 0; m < 4; ++m)
            #pragma unroll
            for (int n = 0; n < 4; ++n)
                acc[m][n] = __builtin_amdgcn_mfma_f32_16x16x32_bf16(av[m], bv[n], acc[m][n], 0, 0, 0);
        __syncthreads();
    }

    // epilogue: +h_b, *q -> qc (bf16)
    int rbase = (l >> 4) * 4;
    #pragma unroll
    for (int n = 0; n < 4; ++n) {
        int col = bn + wc * 64 + n * 16 + lr;
        float hb = h_b[col];
        #pragma unroll
        for (int m = 0; m < 4; ++m) {
            long rowb = arow0 + wr * 64 + m * 16 + rbase;
            #pragma unroll
            for (int r = 0; r < 4; ++r) {
                long row = rowb + r;
                float v = acc[m][n][r] + hb;
                float qv = bf2f(q_bf[(size_t)row * CDIM + col]);
                qc_out[(size_t)row * CDIM + col] = f2bf(qv * v);
            }
        }
    }
}

// ---------------- proj GEMM (m97 structure): qc @ proj_w + proj_b -> fp32 ----------------
__global__ __launch_bounds__(256) void proj_gemm(
    const ushort_t* __restrict__ A, const ushort_t* __restrict__ BT,
    const float* __restrict__ bias, float* __restrict__ C)
{
    __shared__ __align__(16) ushort_t As[128 * 32];
    __shared__ __align__(16) ushort_t Bs[128 * 32];
    int tid = threadIdx.x;
    int w = tid >> 6, l = tid & 63;
    int bn = blockIdx.x * 128;
    long arow0 = (long)blockIdx.y * 128;

    int wr = w >> 1, wc = w & 1;
    int lr = l & 15, lk = (l >> 4) * 8;
    int sr = l >> 2;
    int sc = (l & 3) * 8;

    f32x4 acc[4][4] = {};

    for (int kt = 0; kt < 8; ++kt) {
        int k0 = kt << 5;
        #pragma unroll
        for (int jj = 0; jj < 2; ++jj) {
            int j = w * 2 + jj;
            int r = j * 16 + sr;
            gload16(A + (arow0 + r) * CDIM + (k0 + sc), &As[j * 512]);
            gload16(BT + (long)(bn + r) * 256 + (k0 + sc), &Bs[j * 512]);
        }
        __syncthreads();
        bf16x8 av[4], bv[4];
        #pragma unroll
        for (int m = 0; m < 4; ++m)
            av[m] = *reinterpret_cast<const bf16x8*>(&As[(wr * 64 + m * 16 + lr) * 32 + lk]);
        #pragma unroll
        for (int n = 0; n < 4; ++n)
            bv[n] = *reinterpret_cast<const bf16x8*>(&Bs[(wc * 64 + n * 16 + lr) * 32 + lk]);
        #pragma unroll
        for (int m = 0; m < 4; ++m)
            #pragma unroll
            for (int n = 0; n < 4; ++n)
                acc[m][n] = __builtin_amdgcn_mfma_f32_16x16x32_bf16(av[m], bv[n], acc[m][n], 0, 0, 0);
        __syncthreads();
    }

    int rbase = (l >> 4) * 4;
    #pragma unroll
    for (int n = 0; n < 4; ++n) {
        int col = bn + wc * 64 + n * 16 + lr;
        float bia = bias[col];
        #pragma unroll
        for (int m = 0; m < 4; ++m) {
            long rowb = arow0 + wr * 64 + m * 16 + rbase;
            #pragma unroll
            for (int r = 0; r < 4; ++r)
                C[(size_t)(rowb + r) * CDIM + col] = acc[m][n][r] + bia;
        }
    }
}

extern "C" void kernel_launch(void* const* d_in, const int* in_sizes, int n_in,
                              void* d_out, int out_size, void* d_ws, size_t ws_size,
                              hipStream_t stream) {
    const float* x      = (const float*)d_in[0];
    const float* f_w    = (const float*)d_in[1];
    const float* f_b    = (const float*)d_in[2];
    const float* h_w    = (const float*)d_in[3];
    const float* h_b    = (const float*)d_in[4];
    const float* proj_w = (const float*)d_in[5];
    const float* proj_b = (const float*)d_in[6];
    const float* conv_w[3] = { (const float*)d_in[7],  (const float*)d_in[11], (const float*)d_in[15] };
    const float* conv_b[3] = { (const float*)d_in[8],  (const float*)d_in[12], (const float*)d_in[16] };
    const float* ln_g[3]   = { (const float*)d_in[9],  (const float*)d_in[13], (const float*)d_in[17] };
    const float* ln_b[3]   = { (const float*)d_in[10], (const float*)d_in[14], (const float*)d_in[18] };

    const size_t MC = (size_t)MTOT * CDIM;
    const size_t PADC = (size_t)BATCH * PADROWS * CDIM;
    char* w = (char*)d_ws;
    ushort_t* x_bf  = (ushort_t*)w;  w += MC * 2;
    ushort_t* q_bf  = (ushort_t*)w;  w += MC * 2;
    ushort_t* ctxF  = (ushort_t*)w;  w += PADC * 2;   // ctxF..ctx2 contiguous
    ushort_t* ctx0  = (ushort_t*)w;  w += PADC * 2;
    ushort_t* ctx1  = (ushort_t*)w;  w += PADC * 2;
    ushort_t* ctx2  = (ushort_t*)w;  w += PADC * 2;
    float* gates    = (float*)w;     w += (size_t)MTOT * 4 * 4;
    float* partial  = (float*)w;     w += (size_t)8 * 32 * CDIM * 4;
    float* meanv    = (float*)w;     w += (size_t)8 * CDIM * 4;
    ushort_t* f_wT  = (ushort_t*)w;  w += (size_t)512 * 256 * 2;
    ushort_t* convT0 = (ushort_t*)w; w += (size_t)768 * 256 * 2;
    ushort_t* convT1 = (ushort_t*)w; w += (size_t)1280 * 256 * 2;
    ushort_t* convT2 = (ushort_t*)w; w += (size_t)1792 * 256 * 2;
    ushort_t* h_wT   = (ushort_t*)w; w += (size_t)256 * 256 * 2;
    ushort_t* proj_wT = (ushort_t*)w; w += (size_t)256 * 256 * 2;
    ushort_t* qc_bf = x_bf;          // reuse (x_bf consumed after fea_gemm)

    dim3 blk(256);

    cvt_gates<<<dim3(MTOT / 4), blk, 0, stream>>>(x, f_w, f_b, x_bf, gates);
    prep_weights<<<dim3(1216), blk, 0, stream>>>(f_w, conv_w[0], conv_w[1], conv_w[2],
        h_w, proj_w, f_wT, convT0, convT1, convT2, h_wT, proj_wT);
    zero_guards_all<<<dim3(512), blk, 0, stream>>>(ctxF);

    // feature GEMM (q + ctx)
    fea_gemm<<<dim3(4, 512), blk, 0, stream>>>(x_bf, f_wT, f_b, q_bf, ctxF);

    // three fused conv+GELU+LN levels (best verified structure)
    conv_fused<<<dim3(512), dim3(512), 0, stream>>>(ctxF, convT0, conv_b[0],
        ln_g[0], ln_b[0], ctx0, 3, 768);
    conv_fused<<<dim3(512), dim3(512), 0, stream>>>(ctx0, convT1, conv_b[1],
        ln_g[1], ln_b[1], ctx1, 5, 1280);
    conv_fused<<<dim3(512), dim3(512), 0, stream>>>(ctx1, convT2, conv_b[2],
        ln_g[2], ln_b[2], ctx2, 7, 1792);

    // global context mean (final ctx is ctx2)
    col_mean_partial<<<dim3(BATCH, 32), blk, 0, stream>>>(ctx2, partial);
    col_mean_final<<<dim3(BATCH), blk, 0, stream>>>(partial, meanv);

    // fused combine + h-GEMM + q-mul -> qc_bf (overwrites x_bf)
    combine_h_gemm<<<dim3(2, 512), blk, 0, stream>>>(ctx0, ctx1, ctx2,
        gates, meanv, q_bf, h_wT, h_b, qc_bf);

    // final projection: qc @ proj_w + proj_b -> d_out (fp32)
    proj_gemm<<<dim3(2, 512), blk, 0, stream>>>(qc_bf, proj_wT, proj_b,
        (float*)d_out);
}

// Round 14
// 359.083 us; speedup vs baseline: 1.0827x; 1.0593x over previous
//
#include <hip/hip_runtime.h>
#include <math.h>

#define CDIM 256
#define LSEQ 8192
#define BATCH 8
#define MTOT (BATCH * LSEQ)
#define PADROWS 8208           // 8 + 8192 + 8 per batch
#define PAD0 8

typedef unsigned short ushort_t;
typedef unsigned int uint_t;

typedef __bf16 bf16x8 __attribute__((ext_vector_type(8)));
typedef float f32x4 __attribute__((ext_vector_type(4)));

__device__ __forceinline__ ushort_t f2bf(float f) {
    union { float f; uint_t u; } v; v.f = f;
    uint_t u = v.u;
    return (ushort_t)((u + 0x7FFFu + ((u >> 16) & 1u)) >> 16);  // RNE
}
__device__ __forceinline__ float bf2f(ushort_t h) {
    union { uint_t u; float f; } v; v.u = ((uint_t)h) << 16;
    return v.f;
}
__device__ __forceinline__ float gelu_exact(float x) {
    return 0.5f * x * (1.0f + erff(x * 0.70710678118654752440f));
}

// async global(16B/lane) -> LDS (wave-uniform base + lane*16)
__device__ __forceinline__ void gload16(const ushort_t* g, ushort_t* lds) {
    __builtin_amdgcn_global_load_lds(
        reinterpret_cast<__attribute__((address_space(1))) uint_t*>(
            reinterpret_cast<uintptr_t>(g)),
        reinterpret_cast<__attribute__((address_space(3))) uint_t*>(
            reinterpret_cast<uintptr_t>(lds)),
        16, 0, 0);
}

// ---------------- fused x: bf16 convert + gates sliver ----------------
__global__ __launch_bounds__(256) void cvt_gates(
    const float* __restrict__ x, const float* __restrict__ f_w,
    const float* __restrict__ f_b,
    ushort_t* __restrict__ x_bf, float* __restrict__ gates)
{
    __shared__ float fcol[256][4];
    int tid = threadIdx.x;
    #pragma unroll
    for (int j = 0; j < 4; ++j) fcol[tid][j] = f_w[(size_t)tid * 516 + 512 + j];
    __syncthreads();
    int w = tid >> 6, l = tid & 63;
    size_t t = (size_t)blockIdx.x * 4 + w;
    float4 xv = ((const float4*)(x + t * CDIM))[l];
    ((ushort4*)(x_bf + t * CDIM))[l] =
        make_ushort4(f2bf(xv.x), f2bf(xv.y), f2bf(xv.z), f2bf(xv.w));
    int c = l * 4;
    float a[4];
    #pragma unroll
    for (int j = 0; j < 4; ++j)
        a[j] = xv.x * fcol[c][j] + xv.y * fcol[c + 1][j] + xv.z * fcol[c + 2][j] + xv.w * fcol[c + 3][j];
    #pragma unroll
    for (int off = 32; off >= 1; off >>= 1)
        #pragma unroll
        for (int j = 0; j < 4; ++j) a[j] += __shfl_xor(a[j], off);
    if (l == 0) {
        #pragma unroll
        for (int j = 0; j < 4; ++j) gates[t * 4 + j] = a[j] + f_b[512 + j];
    }
}

// ---------------- single-launch weight prep ----------------
__global__ __launch_bounds__(256) void prep_weights(
    const float* __restrict__ f_w,  const float* __restrict__ c0,
    const float* __restrict__ c1,   const float* __restrict__ c2,
    const float* __restrict__ h_w,  const float* __restrict__ p_w,
    ushort_t* __restrict__ f_wT, ushort_t* __restrict__ c0T,
    ushort_t* __restrict__ c1T,  ushort_t* __restrict__ c2T,
    ushort_t* __restrict__ h_wT, ushort_t* __restrict__ p_wT)
{
    __shared__ float t[32][33];
    int r = blockIdx.x;
    const float* in; ushort_t* out; int Kt, ldin;
    if (r < 128)              { in = f_w; out = f_wT; Kt = 8;  ldin = 516; }
    else if ((r -= 128) < 192){ in = c0;  out = c0T;  Kt = 24; ldin = 256; }
    else if ((r -= 192) < 320){ in = c1;  out = c1T;  Kt = 40; ldin = 256; }
    else if ((r -= 320) < 448){ in = c2;  out = c2T;  Kt = 56; ldin = 256; }
    else if ((r -= 448) < 64) { in = h_w; out = h_wT; Kt = 8;  ldin = 256; }
    else                      { r -= 64; in = p_w; out = p_wT; Kt = 8; ldin = 256; }
    int K = Kt * 32;
    int k0 = (r % Kt) * 32, n0 = (r / Kt) * 32;
    int tx = threadIdx.x & 31, ty = threadIdx.x >> 5;
    #pragma unroll
    for (int i = 0; i < 4; i++) {
        int k = k0 + ty + i * 8;
        t[ty + i * 8][tx] = in[(size_t)k * ldin + n0 + tx];
    }
    __syncthreads();
    #pragma unroll
    for (int i = 0; i < 4; i++) {
        int n = n0 + ty + i * 8;
        out[(size_t)n * K + k0 + tx] = f2bf(t[tx][ty + i * 8]);
    }
}

// ---------------- zero guard bands of 4 contiguous ctx_pad buffers ----------------
__global__ __launch_bounds__(256) void zero_guards_all(ushort_t* __restrict__ ctx_base) {
    int i = blockIdx.x * 256 + threadIdx.x;
    int buf = i >> 15;
    int j = i & 32767;
    int c = j & 255;
    int rr = (j >> 8) & 15;
    int b = j >> 12;
    size_t row = (size_t)b * PADROWS + ((rr < 8) ? rr : (PADROWS - 16 + rr));
    ctx_base[((size_t)buf * BATCH * PADROWS + row) * CDIM + c] = 0;
}

// ---------------- generic MFMA GEMM (m97 structure): 128x128 tile ----------------
// XCD-chunked tile swizzle: consecutive hw block ids (which round-robin XCDs)
// are remapped so each XCD owns a contiguous tile range; the grid.x col-blocks
// sharing an A row-panel land on the SAME XCD -> panel fetched once per L2.
// MODE 0: C[row*256+col] = acc + bias  (fp32 out)
// MODE 1: fea: col<256 -> q_bf(bf16) ; col>=256 -> ctx_pad (padded rows, bf16)
// MODE 2: qc in-place: q_out[idx] = bf16(bf2f(q_out[idx]) * (acc+bias))
template <int MODE>
__global__ __launch_bounds__(256) void gemm_bf16(
    const ushort_t* __restrict__ A, const ushort_t* __restrict__ BT,
    const float* __restrict__ bias,
    float* __restrict__ C, ushort_t* __restrict__ q_out, ushort_t* __restrict__ ctx_pad,
    int Ktot)
{
    __shared__ __align__(16) ushort_t As[128 * 32];
    __shared__ __align__(16) ushort_t Bs[128 * 32];
    int tid = threadIdx.x;
    int w = tid >> 6, l = tid & 63;

    // chunked XCD swizzle (N = gridDim.x*gridDim.y divisible by 8)
    int hw = blockIdx.x + gridDim.x * blockIdx.y;
    int N = gridDim.x * gridDim.y;
    int tile = (hw & 7) * (N >> 3) + (hw >> 3);
    int bx = tile % gridDim.x;
    int by = tile / gridDim.x;

    int bn = bx * 128;
    long arow0 = (long)by * 128;
    int crow0 = by * 128;

    int wr = w >> 1, wc = w & 1;
    int lr = l & 15, lk = (l >> 4) * 8;
    int sr = l >> 2;
    int sc = (l & 3) * 8;

    f32x4 acc[4][4] = {};

    int nsteps = Ktot >> 5;
    for (int kt = 0; kt < nsteps; ++kt) {
        int k0 = kt << 5;
        #pragma unroll
        for (int jj = 0; jj < 2; ++jj) {
            int j = w * 2 + jj;
            int r = j * 16 + sr;
            gload16(A + (arow0 + r) * CDIM + (k0 + sc), &As[j * 512]);
            gload16(BT + (long)(bn + r) * Ktot + (k0 + sc), &Bs[j * 512]);
        }
        __syncthreads();
        bf16x8 av[4], bv[4];
        #pragma unroll
        for (int m = 0; m < 4; ++m)
            av[m] = *reinterpret_cast<const bf16x8*>(&As[(wr * 64 + m * 16 + lr) * 32 + lk]);
        #pragma unroll
        for (int n = 0; n < 4; ++n)
            bv[n] = *reinterpret_cast<const bf16x8*>(&Bs[(wc * 64 + n * 16 + lr) * 32 + lk]);
        #pragma unroll
        for (int m = 0; m < 4; ++m)
            #pragma unroll
            for (int n = 0; n < 4; ++n)
                acc[m][n] = __builtin_amdgcn_mfma_f32_16x16x32_bf16(av[m], bv[n], acc[m][n], 0, 0, 0);
        __syncthreads();
    }

    int rbase = (l >> 4) * 4;
    #pragma unroll
    for (int n = 0; n < 4; ++n) {
        int col = bn + wc * 64 + n * 16 + lr;
        float bia = bias[col];
        #pragma unroll
        for (int m = 0; m < 4; ++m) {
            int rowb = crow0 + wr * 64 + m * 16 + rbase;
            #pragma unroll
            for (int r = 0; r < 4; ++r) {
                float v = acc[m][n][r] + bia;
                int row = rowb + r;
                if (MODE == 0) {
                    C[(size_t)row * CDIM + col] = v;
                } else if (MODE == 1) {
                    if (col < CDIM) {
                        q_out[(size_t)row * CDIM + col] = f2bf(v);
                    } else {
                        int bb = row >> 13, tb = row & (LSEQ - 1);
                        ctx_pad[((size_t)bb * PADROWS + PAD0 + tb) * CDIM + (col - CDIM)] = f2bf(v);
                    }
                } else {
                    size_t idx = (size_t)row * CDIM + col;
                    q_out[idx] = f2bf(bf2f(q_out[idx]) * v);
                }
            }
        }
    }
}

// ---- staging helpers for conv_fused (BM=128, 512 thr) ----
__device__ __forceinline__ void stageA128(const ushort_t* Arow0, int cc,
                                          ushort_t* asb, int tid, int w) {
    int row = tid >> 2, cp = tid & 3;
    int cg = cp ^ ((row >> 1) & 3);
    gload16(Arow0 + (size_t)row * CDIM + cc * 32 + cg * 8, asb + (size_t)(w * 64) * 8);
    if (tid < 64) {
        int o2 = 512 + tid;
        int row2 = o2 >> 2, cp2 = o2 & 3;
        int cg2 = cp2 ^ ((row2 >> 1) & 3);
        gload16(Arow0 + (size_t)row2 * CDIM + cc * 32 + cg2 * 8, asb + (size_t)512 * 8);
    }
}
__device__ __forceinline__ void stageB128(const ushort_t* BT, int Ktot, int koffB,
                                          ushort_t* bsb, int tid) {
    #pragma unroll
    for (int i = 0; i < 2; ++i) {
        int o = tid + i * 512;
        int n = o >> 2, cp = o & 3;
        int cg = cp ^ ((n >> 1) & 3);
        gload16(BT + (size_t)n * Ktot + koffB + cg * 8,
                bsb + (size_t)((o >> 6) * 64) * 8);
    }
}

// ---------------- fused conv: BM=128, BN=256, 512 thr, 2 blocks/CU ----------------
__global__ __launch_bounds__(512, 4) void conv_fused(
    const ushort_t* __restrict__ A, const ushort_t* __restrict__ BT,
    const float* __restrict__ bias,
    const float* __restrict__ lng, const float* __restrict__ lnb,
    ushort_t* __restrict__ ctx_out, int KW, int Ktot)
{
    __shared__ __align__(16) ushort_t As2[2][144 * 32];  // 18432 B
    __shared__ __align__(16) ushort_t Bs[2][256 * 32];   // 32768 B

    int tid = threadIdx.x;
    int w = tid >> 6, l = tid & 63;
    int by = blockIdx.x;
    int b = by >> 6;
    int tloc = (by & 63) << 7;
    const ushort_t* Arow0 = A + ((size_t)b * PADROWS + PAD0 + tloc - 8) * CDIM;

    int wr = w >> 2;
    int wc = w & 3;
    int lr = l & 15;
    int quad = l >> 4;

    int P = KW >> 1;
    int hoff = 8 - P;
    f32x4 acc[4][4] = {};

    stageA128(Arow0, 0, As2[0], tid, w);
    stageB128(BT, Ktot, 0, Bs[0], tid);
    __syncthreads();

    int nIt = KW * 8;
    int it = 0;
    for (int c = 0; c < 8; ++c) {
        for (int tap = 0; tap < KW; ++tap, ++it) {
            if (tap == 0 && c < 7)
                stageA128(Arow0, c + 1, As2[(c + 1) & 1], tid, w);
            if (it + 1 < nIt) {
                int tapn = tap + 1, cn = c;
                if (tapn == KW) { tapn = 0; cn = c + 1; }
                stageB128(BT, Ktot, tapn * 256 + cn * 32, Bs[(it + 1) & 1], tid);
            }
            const ushort_t* asb = As2[c & 1];
            const ushort_t* bsb = Bs[it & 1];
            bf16x8 av[4], bv[4];
            #pragma unroll
            for (int m = 0; m < 4; ++m) {
                int row = wr * 64 + m * 16 + lr + tap + hoff;
                int cs = quad ^ ((row >> 1) & 3);
                av[m] = *reinterpret_cast<const bf16x8*>(&asb[row * 32 + cs * 8]);
            }
            #pragma unroll
            for (int n = 0; n < 4; ++n) {
                int nn = wc * 64 + n * 16 + lr;
                int cs = quad ^ ((nn >> 1) & 3);
                bv[n] = *reinterpret_cast<const bf16x8*>(&bsb[nn * 32 + cs * 8]);
            }
            #pragma unroll
            for (int m = 0; m < 4; ++m)
                #pragma unroll
                for (int n = 0; n < 4; ++n)
                    acc[m][n] = __builtin_amdgcn_mfma_f32_16x16x32_bf16(av[m], bv[n], acc[m][n], 0, 0, 0);
            __syncthreads();
        }
    }

    float* rs = (float*)&Bs[0][0];
    float* rq = rs + 512;
    float bias_c[4], lng_c[4], lnb_c[4];
    #pragma unroll
    for (int n = 0; n < 4; ++n) {
        int col = wc * 64 + n * 16 + lr;
        bias_c[n] = bias[col];
        lng_c[n] = lng[col];
        lnb_c[n] = lnb[col];
    }
    #pragma unroll
    for (int m = 0; m < 4; ++m) {
        #pragma unroll
        for (int r = 0; r < 4; ++r) {
            float s = 0.0f, sq = 0.0f;
            #pragma unroll
            for (int n = 0; n < 4; ++n) {
                float v = acc[m][n][r] + bias_c[n];
                v = gelu_exact(v);
                acc[m][n][r] = v;
                s += v; sq += v * v;
            }
            s += __shfl_xor(s, 1);  sq += __shfl_xor(sq, 1);
            s += __shfl_xor(s, 2);  sq += __shfl_xor(sq, 2);
            s += __shfl_xor(s, 4);  sq += __shfl_xor(sq, 4);
            s += __shfl_xor(s, 8);  sq += __shfl_xor(sq, 8);
            if (lr == 0) {
                int rl = wr * 64 + m * 16 + quad * 4 + r;
                rs[rl * 4 + wc] = s;
                rq[rl * 4 + wc] = sq;
            }
        }
    }
    __syncthreads();
    #pragma unroll
    for (int m = 0; m < 4; ++m) {
        #pragma unroll
        for (int r = 0; r < 4; ++r) {
            int rl = wr * 64 + m * 16 + quad * 4 + r;
            float mean = (rs[rl * 4] + rs[rl * 4 + 1] + rs[rl * 4 + 2] + rs[rl * 4 + 3]) * (1.0f / 256.0f);
            float var = (rq[rl * 4] + rq[rl * 4 + 1] + rq[rl * 4 + 2] + rq[rl * 4 + 3]) * (1.0f / 256.0f) - mean * mean;
            float inv = rsqrtf(var + 1e-3f);
            int trow = tloc + rl;
            ushort_t* cp = ctx_out + ((size_t)b * PADROWS + PAD0 + trow) * CDIM;
            #pragma unroll
            for (int n = 0; n < 4; ++n) {
                int col = wc * 64 + n * 16 + lr;
                float y = (acc[m][n][r] - mean) * inv * lng_c[n] + lnb_c[n];
                cp[col] = f2bf(y);
            }
        }
    }
}

// ---------------- column mean over L (two stage) ----------------
__global__ __launch_bounds__(256) void col_mean_partial(const ushort_t* __restrict__ ctx_pad,
                                                        float* __restrict__ partial) {
    int b = blockIdx.x, chunk = blockIdx.y, c = threadIdx.x;
    const ushort_t* base = ctx_pad + ((size_t)b * PADROWS + PAD0 + chunk * 256) * CDIM + c;
    float s = 0.0f;
    for (int r = 0; r < 256; ++r) s += bf2f(base[(size_t)r * CDIM]);
    partial[((size_t)b * 32 + chunk) * CDIM + c] = s;
}

__global__ __launch_bounds__(256) void col_mean_final(const float* __restrict__ partial,
                                                      float* __restrict__ meanv) {
    int b = blockIdx.x, c = threadIdx.x;
    float s = 0.0f;
    for (int i = 0; i < 32; ++i) s += partial[((size_t)b * 32 + i) * CDIM + c];
    meanv[b * CDIM + c] = s * (1.0f / (float)LSEQ);
}

// ---------------- A_bf = bf16(sum_l gate_l*ctx_l + meanv*g3) ----------------
__global__ __launch_bounds__(256) void finalize_A(
    const ushort_t* __restrict__ c0buf, const ushort_t* __restrict__ c1buf,
    const ushort_t* __restrict__ c2buf,
    const float* __restrict__ meanv, const float* __restrict__ gates,
    ushort_t* __restrict__ A_bf)
{
    int i = blockIdx.x * 256 + threadIdx.x;   // 8 channels per thread
    int t = i >> 5;
    int c8 = (i & 31) * 8;
    int b = t >> 13, tb = t & (LSEQ - 1);
    size_t pidx = ((size_t)b * PADROWS + PAD0 + tb) * CDIM + c8;
    const float* g = gates + (size_t)t * 4;
    float g0 = g[0], g1 = g[1], g2 = g[2], g3 = g[3];
    ushort4 a0 = *(const ushort4*)(c0buf + pidx);
    ushort4 a1 = *(const ushort4*)(c0buf + pidx + 4);
    ushort4 b0 = *(const ushort4*)(c1buf + pidx);
    ushort4 b1 = *(const ushort4*)(c1buf + pidx + 4);
    ushort4 d0 = *(const ushort4*)(c2buf + pidx);
    ushort4 d1 = *(const ushort4*)(c2buf + pidx + 4);
    const float* mv = meanv + b * CDIM + c8;
    ushort_t out[8];
    ushort_t va[8] = { a0.x, a0.y, a0.z, a0.w, a1.x, a1.y, a1.z, a1.w };
    ushort_t vb[8] = { b0.x, b0.y, b0.z, b0.w, b1.x, b1.y, b1.z, b1.w };
    ushort_t vd[8] = { d0.x, d0.y, d0.z, d0.w, d1.x, d1.y, d1.z, d1.w };
    #pragma unroll
    for (int j = 0; j < 8; ++j) {
        float v = bf2f(va[j]) * g0 + bf2f(vb[j]) * g1 + bf2f(vd[j]) * g2 + mv[j] * g3;
        out[j] = f2bf(v);
    }
    *(ushort4*)(A_bf + (size_t)t * CDIM + c8)     = make_ushort4(out[0], out[1], out[2], out[3]);
    *(ushort4*)(A_bf + (size_t)t * CDIM + c8 + 4) = make_ushort4(out[4], out[5], out[6], out[7]);
}

extern "C" void kernel_launch(void* const* d_in, const int* in_sizes, int n_in,
                              void* d_out, int out_size, void* d_ws, size_t ws_size,
                              hipStream_t stream) {
    const float* x      = (const float*)d_in[0];
    const float* f_w    = (const float*)d_in[1];
    const float* f_b    = (const float*)d_in[2];
    const float* h_w    = (const float*)d_in[3];
    const float* h_b    = (const float*)d_in[4];
    const float* proj_w = (const float*)d_in[5];
    const float* proj_b = (const float*)d_in[6];
    const float* conv_w[3] = { (const float*)d_in[7],  (const float*)d_in[11], (const float*)d_in[15] };
    const float* conv_b[3] = { (const float*)d_in[8],  (const float*)d_in[12], (const float*)d_in[16] };
    const float* ln_g[3]   = { (const float*)d_in[9],  (const float*)d_in[13], (const float*)d_in[17] };
    const float* ln_b[3]   = { (const float*)d_in[10], (const float*)d_in[14], (const float*)d_in[18] };

    const size_t MC = (size_t)MTOT * CDIM;
    const size_t PADC = (size_t)BATCH * PADROWS * CDIM;
    char* w = (char*)d_ws;
    ushort_t* x_bf  = (ushort_t*)w;  w += MC * 2;
    ushort_t* q_bf  = (ushort_t*)w;  w += MC * 2;
    ushort_t* ctxF  = (ushort_t*)w;  w += PADC * 2;   // ctxF..ctx2 contiguous
    ushort_t* ctx0  = (ushort_t*)w;  w += PADC * 2;
    ushort_t* ctx1  = (ushort_t*)w;  w += PADC * 2;
    ushort_t* ctx2  = (ushort_t*)w;  w += PADC * 2;
    float* gates    = (float*)w;     w += (size_t)MTOT * 4 * 4;
    float* partial  = (float*)w;     w += (size_t)8 * 32 * CDIM * 4;
    float* meanv    = (float*)w;     w += (size_t)8 * CDIM * 4;
    ushort_t* f_wT  = (ushort_t*)w;  w += (size_t)512 * 256 * 2;
    ushort_t* convT0 = (ushort_t*)w; w += (size_t)768 * 256 * 2;
    ushort_t* convT1 = (ushort_t*)w; w += (size_t)1280 * 256 * 2;
    ushort_t* convT2 = (ushort_t*)w; w += (size_t)1792 * 256 * 2;
    ushort_t* h_wT   = (ushort_t*)w; w += (size_t)256 * 256 * 2;
    ushort_t* proj_wT = (ushort_t*)w; w += (size_t)256 * 256 * 2;
    ushort_t* A_bf = x_bf;           // reuse (x_bf consumed after fea gemm)

    dim3 blk(256);

    cvt_gates<<<dim3(MTOT / 4), blk, 0, stream>>>(x, f_w, f_b, x_bf, gates);
    prep_weights<<<dim3(1216), blk, 0, stream>>>(f_w, conv_w[0], conv_w[1], conv_w[2],
        h_w, proj_w, f_wT, convT0, convT1, convT2, h_wT, proj_wT);
    zero_guards_all<<<dim3(512), blk, 0, stream>>>(ctxF);

    // feature GEMM (q + ctx), XCD-chunk swizzled
    gemm_bf16<1><<<dim3(4, 512), blk, 0, stream>>>(x_bf, f_wT, f_b,
        nullptr, q_bf, ctxF, 256);

    // three fused conv+GELU+LN levels (best verified structure)
    conv_fused<<<dim3(512), dim3(512), 0, stream>>>(ctxF, convT0, conv_b[0],
        ln_g[0], ln_b[0], ctx0, 3, 768);
    conv_fused<<<dim3(512), dim3(512), 0, stream>>>(ctx0, convT1, conv_b[1],
        ln_g[1], ln_b[1], ctx1, 5, 1280);
    conv_fused<<<dim3(512), dim3(512), 0, stream>>>(ctx1, convT2, conv_b[2],
        ln_g[2], ln_b[2], ctx2, 7, 1792);

    // global context mean (final ctx is ctx2)
    col_mean_partial<<<dim3(BATCH, 32), blk, 0, stream>>>(ctx2, partial);
    col_mean_final<<<dim3(BATCH), blk, 0, stream>>>(partial, meanv);

    // combine levels: A_bf = bf16(sum gate_l*ctx_l + mean*g3)
    finalize_A<<<dim3(MTOT * 32 / 256), blk, 0, stream>>>(ctx0, ctx1, ctx2,
        meanv, gates, A_bf);

    // h GEMM with fused q .* (.) epilogue (swizzled): q_bf <- bf16(q_bf * ctxh)
    gemm_bf16<2><<<dim3(2, 512), blk, 0, stream>>>(A_bf, h_wT, h_b,
        nullptr, q_bf, nullptr, 256);
    // final projection (swizzled): qc @ proj_w -> d_out (fp32)
    gemm_bf16<0><<<dim3(2, 512), blk, 0, stream>>>(q_bf, proj_wT, proj_b,
        (float*)d_out, nullptr, nullptr, 256);
}